// Round 5
// baseline (233.212 us; speedup 1.0000x reference)
//
#include <hip/hip_runtime.h>

#define D 128

typedef __attribute__((ext_vector_type(8))) short short8x;
typedef __attribute__((ext_vector_type(4))) float f32x4;

// ---- bf16 helpers (manual RNE) ----
__device__ inline unsigned int f2bf(float f) {
    unsigned int u = __builtin_bit_cast(unsigned int, f);
    return (u + 0x7fffu + ((u >> 16) & 1u)) >> 16;
}
__device__ inline float bflo(unsigned int v) {
    return __builtin_bit_cast(float, v << 16);
}
__device__ inline float bfhi(unsigned int v) {
    return __builtin_bit_cast(float, v & 0xffff0000u);
}
__device__ inline unsigned int pack2(float lo, float hi) {
    return f2bf(lo) | (f2bf(hi) << 16);
}

// ================= W pre-pack: lane-linear bf16 B fragments =================
__global__ __launch_bounds__(256) void pack_w(
    const float* __restrict__ W1, const float* __restrict__ W2,
    uint4* __restrict__ pack)
{
    int e = blockIdx.x * 256 + threadIdx.x;      // 0..4095
    const float* W = (e & 2048) ? W2 : W1;
    int f = (e >> 6) & 31, l = e & 63;
    int kt = f >> 3, nt = f & 7;
    int k0 = kt * 32 + (l >> 4) * 8;
    int col = nt * 16 + (l & 15);
    unsigned int v[8];
#pragma unroll
    for (int j = 0; j < 8; ++j) v[j] = f2bf(W[(size_t)(k0 + j) * D + col]);
    uint4 o;
    o.x = v[0] | (v[1] << 16);
    o.y = v[2] | (v[3] << 16);
    o.z = v[4] | (v[5] << 16);
    o.w = v[6] | (v[7] << 16);
    pack[e] = o;
}

// ================= MFMA GEMM: out = act(X @ W + b) =================
template <bool IN_BF16, bool RELU, bool OUT_BF16>
__global__ __launch_bounds__(256) void gemm_mfma(
    const void* __restrict__ xin, const uint4* __restrict__ wpack,
    const float* __restrict__ b, void* __restrict__ xout, int n_rows)
{
    __shared__ uint4 xs4[2048];
    __shared__ uint4 ws4[2048];
    const int t = threadIdx.x;
    const int row0 = blockIdx.x * 128;

#pragma unroll
    for (int i = 0; i < 8; ++i) ws4[t + 256 * i] = wpack[t + 256 * i];

    if (IN_BF16) {
        const uint4* g = (const uint4*)xin;
#pragma unroll
        for (int i = 0; i < 8; ++i) {
            int c = t + 256 * i;
            int row = c >> 4, kc = c & 15;
            int grow = row0 + row;
            if (grow < n_rows)
                xs4[row * 16 + (kc ^ (row & 7))] = g[(size_t)grow * 16 + kc];
        }
    } else {
        const float4* g = (const float4*)xin;
#pragma unroll
        for (int i = 0; i < 8; ++i) {
            int c = t + 256 * i;
            int row = c >> 4, kc = c & 15;
            int grow = row0 + row;
            if (grow < n_rows) {
                float4 f0 = g[(size_t)grow * 32 + kc * 2];
                float4 f1 = g[(size_t)grow * 32 + kc * 2 + 1];
                uint4 v;
                v.x = pack2(f0.x, f0.y);
                v.y = pack2(f0.z, f0.w);
                v.z = pack2(f1.x, f1.y);
                v.w = pack2(f1.z, f1.w);
                xs4[row * 16 + (kc ^ (row & 7))] = v;
            }
        }
    }
    __syncthreads();

    const int l = t & 63;
    const int w = t >> 6;
    const int l15 = l & 15;
    const int lk = l >> 4;

    float bias_v[8];
#pragma unroll
    for (int nt = 0; nt < 8; ++nt) bias_v[nt] = b[nt * 16 + l15];

    f32x4 acc[2][8];
#pragma unroll
    for (int rt = 0; rt < 2; ++rt)
#pragma unroll
        for (int nt = 0; nt < 8; ++nt) acc[rt][nt] = (f32x4){0.f, 0.f, 0.f, 0.f};

    const int arow0 = w * 32 + l15;
    const int arow1 = arow0 + 16;

#pragma unroll
    for (int kt = 0; kt < 4; ++kt) {
        int kc0 = kt * 4 + lk;
        short8x a0 = *(const short8x*)&xs4[arow0 * 16 + (kc0 ^ (arow0 & 7))];
        short8x a1 = *(const short8x*)&xs4[arow1 * 16 + (kc0 ^ (arow1 & 7))];
#pragma unroll
        for (int nt = 0; nt < 8; ++nt) {
            short8x bf = *(const short8x*)&ws4[(kt * 8 + nt) * 64 + l];
            acc[0][nt] = __builtin_amdgcn_mfma_f32_16x16x32_bf16(a0, bf, acc[0][nt], 0, 0, 0);
            acc[1][nt] = __builtin_amdgcn_mfma_f32_16x16x32_bf16(a1, bf, acc[1][nt], 0, 0, 0);
        }
    }

    // D layout: col = l&15, row = (l>>4)*4 + reg   [m89-verified]
#pragma unroll
    for (int rt = 0; rt < 2; ++rt) {
#pragma unroll
        for (int r = 0; r < 4; ++r) {
            int row = row0 + w * 32 + rt * 16 + lk * 4 + r;
            if (row >= n_rows) continue;
#pragma unroll
            for (int nt = 0; nt < 8; ++nt) {
                float v = acc[rt][nt][r] + bias_v[nt];
                if (RELU) v = fmaxf(v, 0.f);
                int col = nt * 16 + l15;
                if (OUT_BF16)
                    ((unsigned short*)xout)[(size_t)row * D + col] = (unsigned short)f2bf(v);
                else
                    ((float*)xout)[(size_t)row * D + col] = v;
            }
        }
    }
}

// ================= linked-list build =================
__global__ __launch_bounds__(256) void fill_ll(
    const int* __restrict__ esrc, const int* __restrict__ edst,
    int* __restrict__ head, uint2* __restrict__ nextsrc, int E)
{
    int e = blockIdx.x * 256 + threadIdx.x;
    if (e >= E) return;
    int d = edst[e];
    int s = esrc[e];
    int old = atomicExch(&head[d], e);
    nextsrc[e] = make_uint2((unsigned)old, (unsigned)s);
}

// ================= pull via 4-way interleaved chain walk =================
// 32 lanes per group, 4 nodes per group -> 4 independent dependent-chains in
// flight per group (latency hiding). Named registers only (no scratch).
__global__ __launch_bounds__(256) void pull_ll4(
    const uint2* __restrict__ h2, const int* __restrict__ head,
    const uint2* __restrict__ nextsrc, uint2* __restrict__ agg2, int n_nodes)
{
    int g = blockIdx.x * 8 + (threadIdx.x >> 5);
    int lane = threadIdx.x & 31;
    int base = g * 4;
    if (base >= n_nodes) return;

    int e0 = head[base];
    int e1 = (base + 1 < n_nodes) ? head[base + 1] : -1;
    int e2 = (base + 2 < n_nodes) ? head[base + 2] : -1;
    int e3 = (base + 3 < n_nodes) ? head[base + 3] : -1;

    float4 A0 = make_float4(0.f, 0.f, 0.f, 0.f);
    float4 A1 = make_float4(0.f, 0.f, 0.f, 0.f);
    float4 A2 = make_float4(0.f, 0.f, 0.f, 0.f);
    float4 A3 = make_float4(0.f, 0.f, 0.f, 0.f);

    while ((e0 >= 0) | (e1 >= 0) | (e2 >= 0) | (e3 >= 0)) {
        uint2 n0, n1, n2, n3;
        // issue all chain-pointer loads first (independent -> 4x MLP)
        if (e0 >= 0) n0 = nextsrc[e0];
        if (e1 >= 0) n1 = nextsrc[e1];
        if (e2 >= 0) n2 = nextsrc[e2];
        if (e3 >= 0) n3 = nextsrc[e3];
        if (e0 >= 0) {
            uint2 v = h2[(size_t)n0.y * 32 + lane];
            A0.x += bflo(v.x); A0.y += bfhi(v.x);
            A0.z += bflo(v.y); A0.w += bfhi(v.y);
            e0 = (int)n0.x;
        }
        if (e1 >= 0) {
            uint2 v = h2[(size_t)n1.y * 32 + lane];
            A1.x += bflo(v.x); A1.y += bfhi(v.x);
            A1.z += bflo(v.y); A1.w += bfhi(v.y);
            e1 = (int)n1.x;
        }
        if (e2 >= 0) {
            uint2 v = h2[(size_t)n2.y * 32 + lane];
            A2.x += bflo(v.x); A2.y += bfhi(v.x);
            A2.z += bflo(v.y); A2.w += bfhi(v.y);
            e2 = (int)n2.x;
        }
        if (e3 >= 0) {
            uint2 v = h2[(size_t)n3.y * 32 + lane];
            A3.x += bflo(v.x); A3.y += bfhi(v.x);
            A3.z += bflo(v.y); A3.w += bfhi(v.y);
            e3 = (int)n3.x;
        }
    }

    agg2[(size_t)(base + 0) * 32 + lane] = make_uint2(pack2(A0.x, A0.y), pack2(A0.z, A0.w));
    if (base + 1 < n_nodes)
        agg2[(size_t)(base + 1) * 32 + lane] = make_uint2(pack2(A1.x, A1.y), pack2(A1.z, A1.w));
    if (base + 2 < n_nodes)
        agg2[(size_t)(base + 2) * 32 + lane] = make_uint2(pack2(A2.x, A2.y), pack2(A2.z, A2.w));
    if (base + 3 < n_nodes)
        agg2[(size_t)(base + 3) * 32 + lane] = make_uint2(pack2(A3.x, A3.y), pack2(A3.z, A3.w));
}

// ================= fallback path (f32 atomic scatter) =================
template <bool RELU>
__global__ __launch_bounds__(256) void gemm_bias_act(
    const float* xin, const float* __restrict__ W,
    const float* __restrict__ b, float* xout, int n_rows)
{
    __shared__ float Ws[D * D];
    __shared__ float xs[32 * D];
    const int t = threadIdx.x;
    const int row0 = blockIdx.x * 32;
    const float4* Wv = (const float4*)W;
    float4* Wsv = (float4*)Ws;
#pragma unroll
    for (int i = 0; i < 16; ++i) Wsv[t + 256 * i] = Wv[t + 256 * i];
    const float4* xv = (const float4*)xin;
    float4* xsv = (float4*)xs;
#pragma unroll
    for (int i = 0; i < 4; ++i) {
        int f4 = t + 256 * i;
        int row = row0 + (f4 >> 5);
        if (row < n_rows) xsv[f4] = xv[(size_t)row0 * 32 + f4];
    }
    __syncthreads();
    const int cg = t & 31;
    const int rg = t >> 5;
    float4 bias = ((const float4*)b)[cg];
    float4 acc[4];
#pragma unroll
    for (int ri = 0; ri < 4; ++ri) acc[ri] = make_float4(0.f, 0.f, 0.f, 0.f);
#pragma unroll 4
    for (int k = 0; k < D; k += 4) {
        float4 w0 = Wsv[(k + 0) * 32 + cg];
        float4 w1 = Wsv[(k + 1) * 32 + cg];
        float4 w2 = Wsv[(k + 2) * 32 + cg];
        float4 w3 = Wsv[(k + 3) * 32 + cg];
#pragma unroll
        for (int ri = 0; ri < 4; ++ri) {
            float4 xa = xsv[(rg + 8 * ri) * 32 + (k >> 2)];
            acc[ri].x = fmaf(xa.x, w0.x, fmaf(xa.y, w1.x, fmaf(xa.z, w2.x, fmaf(xa.w, w3.x, acc[ri].x))));
            acc[ri].y = fmaf(xa.x, w0.y, fmaf(xa.y, w1.y, fmaf(xa.z, w2.y, fmaf(xa.w, w3.y, acc[ri].y))));
            acc[ri].z = fmaf(xa.x, w0.z, fmaf(xa.y, w1.z, fmaf(xa.z, w2.z, fmaf(xa.w, w3.z, acc[ri].z))));
            acc[ri].w = fmaf(xa.x, w0.w, fmaf(xa.y, w1.w, fmaf(xa.z, w2.w, fmaf(xa.w, w3.w, acc[ri].w))));
        }
    }
#pragma unroll
    for (int ri = 0; ri < 4; ++ri) {
        int row = row0 + rg + 8 * ri;
        if (row >= n_rows) continue;
        float4 o;
        o.x = acc[ri].x + bias.x; o.y = acc[ri].y + bias.y;
        o.z = acc[ri].z + bias.z; o.w = acc[ri].w + bias.w;
        if (RELU) {
            o.x = fmaxf(o.x, 0.f); o.y = fmaxf(o.y, 0.f);
            o.z = fmaxf(o.z, 0.f); o.w = fmaxf(o.w, 0.f);
        }
        ((float4*)xout)[(size_t)row * 32 + cg] = o;
    }
}

__global__ __launch_bounds__(256) void zero_kernel(float4* p, int n4)
{
    int i = blockIdx.x * 256 + threadIdx.x;
    int stride = gridDim.x * 256;
    for (; i < n4; i += stride) p[i] = make_float4(0.f, 0.f, 0.f, 0.f);
}

__global__ __launch_bounds__(256) void scatter_kernel(
    const float* __restrict__ h, const int* __restrict__ esrc,
    const int* __restrict__ edst, float* __restrict__ agg, long n_items)
{
    long idx = (long)blockIdx.x * 256 + threadIdx.x;
    long stride = (long)gridDim.x * 256;
    for (; idx < n_items; idx += stride) {
        int e = (int)(idx >> 7);
        int c = (int)(idx & 127);
        int s = esrc[e];
        int d = edst[e];
        unsafeAtomicAdd(&agg[(size_t)d * D + c], h[(size_t)s * D + c]);
    }
}

extern "C" void kernel_launch(void* const* d_in, const int* in_sizes, int n_in,
                              void* d_out, int out_size, void* d_ws, size_t ws_size,
                              hipStream_t stream)
{
    const float* x    = (const float*)d_in[0];
    const int*   esrc = (const int*)d_in[1];
    const int*   edst = (const int*)d_in[2];
    const float* W1   = (const float*)d_in[3];
    const float* b1   = (const float*)d_in[4];
    const float* W2   = (const float*)d_in[5];
    const float* b2   = (const float*)d_in[6];
    float* out = (float*)d_out;

    const int N = in_sizes[0] / D;   // 100000
    const int E = in_sizes[1];       // 1600000

    char* ws = (char*)d_ws;
    size_t off_h    = 0;
    size_t off_agg  = off_h + (size_t)N * 256;          // h2: 25.6 MB
    size_t off_next = off_agg + (size_t)N * 256;        // agg2: 25.6 MB
    size_t off_head = off_next + (size_t)E * 8;         // nextsrc: 12.8 MB
    size_t off_pack = (off_head + (size_t)N * 4 + 255) & ~(size_t)255;
    size_t need     = off_pack + 65536;

    const int nblk = (N + 127) / 128;   // 782

    if (ws_size >= need) {
        uint2* h2      = (uint2*)(ws + off_h);
        uint2* agg2    = (uint2*)(ws + off_agg);
        uint2* nextsrc = (uint2*)(ws + off_next);
        int*   head    = (int*)(ws + off_head);
        uint4* pack    = (uint4*)(ws + off_pack);

        hipMemsetAsync(head, 0xFF, (size_t)N * 4, stream);

        pack_w<<<16, 256, 0, stream>>>(W1, W2, pack);

        fill_ll<<<(E + 255) / 256, 256, 0, stream>>>(esrc, edst, head, nextsrc, E);

        gemm_mfma<false, true, true><<<nblk, 256, 0, stream>>>(x, pack, b1, h2, N);

        // 4 chains per lane-group in flight
        pull_ll4<<<(N + 31) / 32, 256, 0, stream>>>(h2, head, nextsrc, agg2, N);

        gemm_mfma<true, false, false><<<nblk, 256, 0, stream>>>(agg2, pack + 2048, b2, out, N);
    } else {
        float* h = (float*)ws;
        const int nb32 = (N + 31) / 32;
        gemm_bias_act<true><<<nb32, 256, 0, stream>>>(x, W1, b1, h, N);
        zero_kernel<<<2048, 256, 0, stream>>>((float4*)out, N * D / 4);
        scatter_kernel<<<8192, 256, 0, stream>>>(h, esrc, edst, out, (long)E * D);
        gemm_bias_act<false><<<nb32, 256, 0, stream>>>(out, W2, b2, out, N);
    }
}